// Round 1
// baseline (247.369 us; speedup 1.0000x reference)
//
#include <hip/hip_runtime.h>

#define NQ 6
#define DIM 64

namespace {

// ---- compile-time ring permutations (CNOT ladder), matching _ring_perm ----
constexpr int ring_entry(int r, int i) {
    int idx = i;
    for (int w = NQ - 1; w >= 0; --w) {
        int c = w;
        int t = (w + r) % NQ;
        int cbit = (idx >> (NQ - 1 - c)) & 1;
        idx ^= cbit << (NQ - 1 - t);
    }
    return idx;
}

struct Perm { int p[DIM]; };

constexpr Perm make_perm(int r) {
    Perm P{};
    for (int i = 0; i < DIM; ++i) P.p[i] = ring_entry(r, i);
    return P;
}

} // namespace

// ---- apply 6 single-qubit gates (one per wire). g = 6 gates x 8 floats ----
// gate layout: [u00r,u00i, u01r,u01i, u10r,u10i, u11r,u11i]
__device__ __forceinline__ void apply_gates(float* pr, float* pi_, const float* __restrict__ g) {
#pragma unroll
    for (int w = 0; w < NQ; ++w) {
        const float u00r = g[w*8+0], u00i = g[w*8+1];
        const float u01r = g[w*8+2], u01i = g[w*8+3];
        const float u10r = g[w*8+4], u10i = g[w*8+5];
        const float u11r = g[w*8+6], u11i = g[w*8+7];
        const int m = 1 << (NQ - 1 - w);
#pragma unroll
        for (int i0 = 0; i0 < DIM; ++i0) {
            if (i0 & m) continue;
            const int i1 = i0 | m;
            const float ar = pr[i0], ai = pi_[i0];
            const float br = pr[i1], bi = pi_[i1];
            pr[i0]  = u00r*ar - u00i*ai + u01r*br - u01i*bi;
            pi_[i0] = u00r*ai + u00i*ar + u01r*bi + u01i*br;
            pr[i1]  = u10r*ar - u10i*ai + u11r*br - u11i*bi;
            pi_[i1] = u10r*ai + u10i*ar + u11r*bi + u11i*br;
        }
    }
}

template<int R>
__device__ __forceinline__ void apply_ring(float* pr, float* pi_) {
    constexpr Perm P = make_perm(R);
    float tr[DIM], ti[DIM];
#pragma unroll
    for (int i = 0; i < DIM; ++i) { tr[i] = pr[P.p[i]]; ti[i] = pi_[P.p[i]]; }
#pragma unroll
    for (int i = 0; i < DIM; ++i) { pr[i] = tr[i]; pi_[i] = ti[i]; }
}

// ---- per-thread gate computation (fallback path, theta is wave-uniform) ----
__device__ __forceinline__ void compute_gates6(const float* __restrict__ th, float* g) {
#pragma unroll
    for (int w = 0; w < NQ; ++w) {
        const float phi = th[w*3+0], theta = th[w*3+1], omega = th[w*3+2];
        float s, c, sa, ca, sb, cb;
        __sincosf(0.5f * theta, &s, &c);
        __sincosf(0.5f * (phi + omega), &sa, &ca);
        __sincosf(0.5f * (phi - omega), &sb, &cb);
        g[w*8+0] =  ca * c;  g[w*8+1] = -sa * c;   // U00 = em*c,      em = ca - i*sa
        g[w*8+2] = -cb * s;  g[w*8+3] = -sb * s;   // U01 = -ep*s,     ep = cb + i*sb
        g[w*8+4] =  cb * s;  g[w*8+5] = -sb * s;   // U10 = conj(ep)*s
        g[w*8+6] =  ca * c;  g[w*8+7] =  sa * c;   // U11 = conj(em)*c
    }
}

// ---- setup kernel: gates (18x8) + G = g*W2 (6x64) + C1/C2 (6+6) into ws ----
// ws layout (floats): [0,144) gates, [144,528) G, [528,534) C1, [534,540) C2+b2
__global__ void setup_kernel(const float* __restrict__ th_s, const float* __restrict__ th_t,
                             const float* __restrict__ ln_g, const float* __restrict__ ln_b,
                             const float* __restrict__ W2, const float* __restrict__ b2,
                             float* __restrict__ ws) {
    const int t = threadIdx.x;
    if (t < 18) {
        const int l = t / 6, w = t % 6;
        const float* th = (l < 2) ? (th_s + (l * 6 + w) * 3) : (th_t + w * 3);
        const float phi = th[0], theta = th[1], omega = th[2];
        float s, c, sa, ca, sb, cb;
        sincosf(0.5f * theta, &s, &c);
        sincosf(0.5f * (phi + omega), &sa, &ca);
        sincosf(0.5f * (phi - omega), &sb, &cb);
        float* g = ws + t * 8;
        g[0] =  ca * c;  g[1] = -sa * c;
        g[2] = -cb * s;  g[3] = -sb * s;
        g[4] =  cb * s;  g[5] = -sb * s;
        g[6] =  ca * c;  g[7] =  sa * c;
    }
    if (t < 384) {
        const int m = t / 64, j = t % 64;
        ws[144 + t] = ln_g[j] * W2[m * 64 + j];
    }
    if (t < 6) {
        float c1 = 0.f, c2 = 0.f;
        for (int j = 0; j < 64; ++j) {
            c1 += ln_g[j] * W2[t * 64 + j];
            c2 += ln_b[j] * W2[t * 64 + j];
        }
        ws[528 + t] = c1;
        ws[534 + t] = c2 + b2[t];
    }
}

template<bool USE_WS>
__global__ __launch_bounds__(256, 2) void qmaml_kernel(
    const float* __restrict__ x,  const float* __restrict__ W1, const float* __restrict__ b1,
    const float* __restrict__ ln_g, const float* __restrict__ ln_b,
    const float* __restrict__ W2, const float* __restrict__ b2,
    const float* __restrict__ th_s, const float* __restrict__ th_t,
    const float* __restrict__ Wc, const float* __restrict__ bc,
    const float* __restrict__ ws, float* __restrict__ out, int nrows) {

    const int row = blockIdx.x * blockDim.x + threadIdx.x;
    if (row >= nrows) return;

    // ---- load x row (lane-private, 64 VGPRs) ----
    float4 xv[16];
    const float4* xp = (const float4*)(x + (long)row * 64);
#pragma unroll
    for (int k = 0; k < 16; ++k) xv[k] = xp[k];

    // ---- fused matvec + relu + LN-stat + folded (g*W2) projection ----
    // z_pre[m] = inv*(A[m] - mu*C1[m]) + C2[m],  A[m] = sum_j relu(h_j)*g_j*W2[m,j]
    float A[6]  = {0.f, 0.f, 0.f, 0.f, 0.f, 0.f};
    float C1[6] = {0.f, 0.f, 0.f, 0.f, 0.f, 0.f};
    float C2[6] = {0.f, 0.f, 0.f, 0.f, 0.f, 0.f};
    float s = 0.f, s2 = 0.f;

    for (int j = 0; j < 64; ++j) {       // rolled: W1 row via wave-uniform s_load
        const float4* wr = (const float4*)(W1 + j * 64);
        float acc = b1[j];
#pragma unroll
        for (int k = 0; k < 16; ++k) {
            const float4 w4 = wr[k];
            acc = fmaf(w4.x, xv[k].x, acc);
            acc = fmaf(w4.y, xv[k].y, acc);
            acc = fmaf(w4.z, xv[k].z, acc);
            acc = fmaf(w4.w, xv[k].w, acc);
        }
        acc = fmaxf(acc, 0.f);
        s += acc; s2 += acc * acc;
        if constexpr (USE_WS) {
            const float* G = ws + 144;
#pragma unroll
            for (int m = 0; m < 6; ++m) A[m] = fmaf(acc, G[m * 64 + j], A[m]);
        } else {
            const float gj = ln_g[j], bj = ln_b[j];
#pragma unroll
            for (int m = 0; m < 6; ++m) {
                const float w2 = W2[m * 64 + j];
                const float gw = gj * w2;
                A[m]  = fmaf(acc, gw, A[m]);
                C1[m] += gw;
                C2[m] = fmaf(bj, w2, C2[m]);
            }
        }
    }

    const float mu  = s  * (1.f / 64.f);
    const float var = s2 * (1.f / 64.f) - mu * mu;
    const float inv = rsqrtf(var + 1e-5f);

    // ---- z = tanh(...), angles, per-wire (cos, sin) ----
    float vc[6], vs[6];
#pragma unroll
    for (int m = 0; m < 6; ++m) {
        float c1v, c2v;
        if constexpr (USE_WS) { c1v = ws[528 + m]; c2v = ws[534 + m]; }
        else                  { c1v = C1[m];       c2v = C2[m] + b2[m]; }
        const float zp = inv * (A[m] - mu * c1v) + c2v;
        const float e  = __expf(2.f * zp);
        const float z  = 1.f - 2.f / (e + 1.f);          // tanh, inf-safe
        const float half = 1.57079632679f * z;           // pi/2 * z, |half| <= pi/2
        vs[m] = __sinf(half);
        vc[m] = __cosf(half);
    }

    // ---- product state (wire 0 = MSB) ----
    float pr[DIM], pim[DIM];
#pragma unroll
    for (int i = 0; i < DIM; ++i) {
        float v = ((i >> 5) & 1) ? vs[0] : vc[0];
        v *= ((i >> 4) & 1) ? vs[1] : vc[1];
        v *= ((i >> 3) & 1) ? vs[2] : vc[2];
        v *= ((i >> 2) & 1) ? vs[3] : vc[3];
        v *= ((i >> 1) & 1) ? vs[4] : vc[4];
        v *= ( i       & 1) ? vs[5] : vc[5];
        pr[i] = v;
        pim[i] = 0.f;
    }

    // ---- 3 entangling layers: shared l=0 (r=1), shared l=1 (r=2), task (r=1) ----
    if constexpr (USE_WS) {
        apply_gates(pr, pim, ws + 0);
        apply_ring<1>(pr, pim);
        apply_gates(pr, pim, ws + 48);
        apply_ring<2>(pr, pim);
        apply_gates(pr, pim, ws + 96);
        apply_ring<1>(pr, pim);
    } else {
        float g[48];
        compute_gates6(th_s, g);
        apply_gates(pr, pim, g);
        apply_ring<1>(pr, pim);
        compute_gates6(th_s + 18, g);
        apply_gates(pr, pim, g);
        apply_ring<2>(pr, pim);
        compute_gates6(th_t, g);
        apply_gates(pr, pim, g);
        apply_ring<1>(pr, pim);
    }

    // ---- <Z_w> readout ----
    float q[6] = {0.f, 0.f, 0.f, 0.f, 0.f, 0.f};
#pragma unroll
    for (int i = 0; i < DIM; ++i) {
        const float p = pr[i] * pr[i] + pim[i] * pim[i];
#pragma unroll
        for (int w = 0; w < 6; ++w) {
            if ((i >> (5 - w)) & 1) q[w] -= p; else q[w] += p;
        }
    }

    // ---- head: out = q @ Wc^T + bc ----
#pragma unroll
    for (int n = 0; n < 5; ++n) {
        float o = bc[n];
#pragma unroll
        for (int w = 0; w < 6; ++w) o = fmaf(q[w], Wc[n * 6 + w], o);
        out[(long)row * 5 + n] = o;
    }
}

extern "C" void kernel_launch(void* const* d_in, const int* in_sizes, int n_in,
                              void* d_out, int out_size, void* d_ws, size_t ws_size,
                              hipStream_t stream) {
    const float* x   = (const float*)d_in[0];
    const float* W1  = (const float*)d_in[1];
    const float* b1  = (const float*)d_in[2];
    const float* lng = (const float*)d_in[3];
    const float* lnb = (const float*)d_in[4];
    const float* W2  = (const float*)d_in[5];
    const float* b2  = (const float*)d_in[6];
    const float* ths = (const float*)d_in[7];
    const float* tht = (const float*)d_in[8];
    const float* Wc  = (const float*)d_in[9];
    const float* bc  = (const float*)d_in[10];
    float* out = (float*)d_out;
    float* ws  = (float*)d_ws;

    const int nrows = in_sizes[0] / 64;          // 131072
    const int grid  = (nrows + 255) / 256;

    if (ws_size >= 540 * sizeof(float)) {
        setup_kernel<<<1, 384, 0, stream>>>(ths, tht, lng, lnb, W2, b2, ws);
        qmaml_kernel<true><<<grid, 256, 0, stream>>>(x, W1, b1, lng, lnb, W2, b2,
                                                     ths, tht, Wc, bc, ws, out, nrows);
    } else {
        qmaml_kernel<false><<<grid, 256, 0, stream>>>(x, W1, b1, lng, lnb, W2, b2,
                                                      ths, tht, Wc, bc, nullptr, out, nrows);
    }
}

// Round 2
// 201.505 us; speedup vs baseline: 1.2276x; 1.2276x over previous
//
#include <hip/hip_runtime.h>
#include <utility>

#define NQ 6
#define DIM 64

namespace {

// ---- compile-time ring permutation (CNOT ladder), matching _ring_perm ----
constexpr int ring_entry(int r, int i) {
    int idx = i;
    for (int w = NQ - 1; w >= 0; --w) {
        int c = w;
        int t = (w + r) % NQ;
        int cbit = (idx >> (NQ - 1 - c)) & 1;
        idx ^= cbit << (NQ - 1 - t);
    }
    return idx;
}

// Logical->physical map after l rings.
// Rings applied in order: R1 (after layer0), R2 (after layer1), R1 (after layer2).
// M0 = id; M1[i] = R1[i]; M2[i] = M1[R2[i]]; M3[i] = M2[R1[i]].
constexpr int Mc(int l, int i) {
    if (l == 1) return ring_entry(1, i);
    if (l == 2) return ring_entry(1, ring_entry(2, i));
    if (l == 3) return ring_entry(1, ring_entry(2, ring_entry(1, i)));
    return i;
}

// k-th index (k in [0,32)) with bit b clear
constexpr int insert_zero(int k, int b) {
    return ((k >> b) << (b + 1)) | (k & ((1 << b) - 1));
}

} // namespace

// ---- one 2x2 complex gate on logical pair (I0,I1), physical via Mc<L> ----
template<int L, int I0, int I1>
__device__ __forceinline__ void gate_pair(float* pr, float* pi_,
    float u00r, float u00i, float u01r, float u01i,
    float u10r, float u10i, float u11r, float u11i) {
    constexpr int p0 = Mc(L, I0);
    constexpr int p1 = Mc(L, I1);
    const float ar = pr[p0], ai = pi_[p0];
    const float br = pr[p1], bi = pi_[p1];
    pr[p0]  = u00r*ar - u00i*ai + u01r*br - u01i*bi;
    pi_[p0] = u00r*ai + u00i*ar + u01r*bi + u01i*br;
    pr[p1]  = u10r*ar - u10i*ai + u11r*br - u11i*bi;
    pi_[p1] = u10r*ai + u10i*ar + u11r*bi + u11i*br;
}

template<int L, int W, int... K>
__device__ __forceinline__ void gate_wire_impl(float* pr, float* pi_,
        const float* __restrict__ g, std::integer_sequence<int, K...>) {
    const float u00r = g[0], u00i = g[1], u01r = g[2], u01i = g[3];
    const float u10r = g[4], u10i = g[5], u11r = g[6], u11i = g[7];
    constexpr int b = 5 - W;
    (gate_pair<L, insert_zero(K, b), insert_zero(K, b) | (1 << b)>(
         pr, pi_, u00r, u00i, u01r, u01i, u10r, u10i, u11r, u11i), ...);
}

template<int L, int... W>
__device__ __forceinline__ void gate_layer_impl(float* pr, float* pi_,
        const float* __restrict__ g, std::integer_sequence<int, W...>) {
    (gate_wire_impl<L, W>(pr, pi_, g + W * 8, std::make_integer_sequence<int, 32>{}), ...);
}

// apply 6 single-qubit gates for layer L (L = ring count already composed)
template<int L>
__device__ __forceinline__ void gate_layer(float* pr, float* pi_, const float* __restrict__ g) {
    gate_layer_impl<L>(pr, pi_, g, std::make_integer_sequence<int, NQ>{});
}

// ---- <Z_w> readout through final map M3 ----
template<int... I>
__device__ __forceinline__ void readout_impl(const float* pr, const float* pi_, float* q,
                                             std::integer_sequence<int, I...>) {
    (([&] {
        constexpr int p = Mc(3, I);
        const float pb = pr[p] * pr[p] + pi_[p] * pi_[p];
        q[0] += ((I >> 5) & 1) ? -pb : pb;
        q[1] += ((I >> 4) & 1) ? -pb : pb;
        q[2] += ((I >> 3) & 1) ? -pb : pb;
        q[3] += ((I >> 2) & 1) ? -pb : pb;
        q[4] += ((I >> 1) & 1) ? -pb : pb;
        q[5] += ( I       & 1) ? -pb : pb;
    }()), ...);
}

// ---- per-thread gate computation (fallback path only) ----
__device__ __forceinline__ void compute_gates6(const float* __restrict__ th, float* g) {
#pragma unroll
    for (int w = 0; w < NQ; ++w) {
        const float phi = th[w*3+0], theta = th[w*3+1], omega = th[w*3+2];
        float s, c, sa, ca, sb, cb;
        __sincosf(0.5f * theta, &s, &c);
        __sincosf(0.5f * (phi + omega), &sa, &ca);
        __sincosf(0.5f * (phi - omega), &sb, &cb);
        g[w*8+0] =  ca * c;  g[w*8+1] = -sa * c;
        g[w*8+2] = -cb * s;  g[w*8+3] = -sb * s;
        g[w*8+4] =  cb * s;  g[w*8+5] = -sb * s;
        g[w*8+6] =  ca * c;  g[w*8+7] =  sa * c;
    }
}

// ---- setup: gates (18x8) + Gt[j][m] = ln_g[j]*W2[m][j] (64x6) + C1/C2 ----
// ws floats: [0,144) gates, [144,528) Gt (j*6+m), [528,534) C1, [534,540) C2+b2
__global__ void setup_kernel(const float* __restrict__ th_s, const float* __restrict__ th_t,
                             const float* __restrict__ ln_g, const float* __restrict__ ln_b,
                             const float* __restrict__ W2, const float* __restrict__ b2,
                             float* __restrict__ ws) {
    const int t = threadIdx.x;
    if (t < 18) {
        const int l = t / 6, w = t % 6;
        const float* th = (l < 2) ? (th_s + (l * 6 + w) * 3) : (th_t + w * 3);
        const float phi = th[0], theta = th[1], omega = th[2];
        float s, c, sa, ca, sb, cb;
        sincosf(0.5f * theta, &s, &c);
        sincosf(0.5f * (phi + omega), &sa, &ca);
        sincosf(0.5f * (phi - omega), &sb, &cb);
        float* g = ws + t * 8;
        g[0] =  ca * c;  g[1] = -sa * c;
        g[2] = -cb * s;  g[3] = -sb * s;
        g[4] =  cb * s;  g[5] = -sb * s;
        g[6] =  ca * c;  g[7] =  sa * c;
    }
    if (t < 384) {
        const int j = t / 6, m = t % 6;
        ws[144 + t] = ln_g[j] * W2[m * 64 + j];
    }
    if (t < 6) {
        float c1 = 0.f, c2 = 0.f;
        for (int j = 0; j < 64; ++j) {
            c1 += ln_g[j] * W2[t * 64 + j];
            c2 += ln_b[j] * W2[t * 64 + j];
        }
        ws[528 + t] = c1;
        ws[534 + t] = c2 + b2[t];
    }
}

template<bool USE_WS>
__global__
__attribute__((amdgpu_flat_work_group_size(256, 256), amdgpu_waves_per_eu(2, 2)))
void qmaml_kernel(
    const float* __restrict__ x,  const float* __restrict__ W1, const float* __restrict__ b1,
    const float* __restrict__ ln_g, const float* __restrict__ ln_b,
    const float* __restrict__ W2, const float* __restrict__ b2,
    const float* __restrict__ th_s, const float* __restrict__ th_t,
    const float* __restrict__ Wc, const float* __restrict__ bc,
    const float* __restrict__ ws, float* __restrict__ out, int nrows) {

    const int row = blockIdx.x * blockDim.x + threadIdx.x;
    if (row >= nrows) return;

    // ---- load x row (lane-private, 64 VGPRs; dies before state phase) ----
    float4 xv[16];
    const float4* xp = (const float4*)(x + (long)row * 64);
#pragma unroll
    for (int k = 0; k < 16; ++k) xv[k] = xp[k];

    // ---- fused matvec + relu + LN-stats + folded (g*W2) projection ----
    float A[6]  = {0.f, 0.f, 0.f, 0.f, 0.f, 0.f};
    float C1[6] = {0.f, 0.f, 0.f, 0.f, 0.f, 0.f};
    float C2[6] = {0.f, 0.f, 0.f, 0.f, 0.f, 0.f};
    float s = 0.f, s2 = 0.f;

    for (int j = 0; j < 64; ++j) {       // rolled; W1 row via wave-uniform s_load
        const float4* wr = (const float4*)(W1 + j * 64);
        float acc = b1[j];
#pragma unroll
        for (int k = 0; k < 16; ++k) {
            const float4 w4 = wr[k];
            acc = fmaf(w4.x, xv[k].x, acc);
            acc = fmaf(w4.y, xv[k].y, acc);
            acc = fmaf(w4.z, xv[k].z, acc);
            acc = fmaf(w4.w, xv[k].w, acc);
        }
        acc = fmaxf(acc, 0.f);
        s += acc; s2 += acc * acc;
        if constexpr (USE_WS) {
            const float* Gt = ws + 144 + j * 6;   // contiguous 6 coeffs, scalar load
#pragma unroll
            for (int m = 0; m < 6; ++m) A[m] = fmaf(acc, Gt[m], A[m]);
        } else {
            const float gj = ln_g[j], bj = ln_b[j];
#pragma unroll
            for (int m = 0; m < 6; ++m) {
                const float w2 = W2[m * 64 + j];
                const float gw = gj * w2;
                A[m]  = fmaf(acc, gw, A[m]);
                C1[m] += gw;
                C2[m] = fmaf(bj, w2, C2[m]);
            }
        }
    }

    const float mu  = s  * (1.f / 64.f);
    const float var = s2 * (1.f / 64.f) - mu * mu;
    const float inv = rsqrtf(var + 1e-5f);

    // ---- z = tanh(...), angles, per-wire (cos, sin) ----
    float vc[6], vs[6];
#pragma unroll
    for (int m = 0; m < 6; ++m) {
        float c1v, c2v;
        if constexpr (USE_WS) { c1v = ws[528 + m]; c2v = ws[534 + m]; }
        else                  { c1v = C1[m];       c2v = C2[m] + b2[m]; }
        const float zp = inv * (A[m] - mu * c1v) + c2v;
        const float e  = __expf(2.f * zp);
        const float z  = 1.f - 2.f / (e + 1.f);          // tanh, inf-safe
        const float half = 1.57079632679f * z;           // pi/2 * z
        vs[m] = __sinf(half);
        vc[m] = __cosf(half);
    }

    float gfall[48];
    const float* g0;
    if constexpr (USE_WS) g0 = ws;
    else { compute_gates6(th_s, gfall); g0 = gfall; }

    // ---- layer-0 gates applied per-wire on the product state (48 instr) ----
    float gar[6], gai[6], gbr[6], gbi[6];
#pragma unroll
    for (int w = 0; w < 6; ++w) {
        const float c = vc[w], sv = vs[w];
        gar[w] = g0[w*8+0]*c + g0[w*8+2]*sv;
        gai[w] = g0[w*8+1]*c + g0[w*8+3]*sv;
        gbr[w] = g0[w*8+4]*c + g0[w*8+6]*sv;
        gbi[w] = g0[w*8+5]*c + g0[w*8+7]*sv;
    }

    // ---- progressive complex tensor product (wire 0 = MSB) ----
    float c2r_[4], c2i_[4];
#pragma unroll
    for (int t = 0; t < 4; ++t) {
        const int a = t >> 1, b = t & 1;
        const float xr = a ? gbr[0] : gar[0], xi = a ? gbi[0] : gai[0];
        const float yr = b ? gbr[1] : gar[1], yi = b ? gbi[1] : gai[1];
        c2r_[t] = xr * yr - xi * yi;
        c2i_[t] = xr * yi + xi * yr;
    }
    float c3r[8], c3i[8];
#pragma unroll
    for (int t = 0; t < 8; ++t) {
        const int h = t >> 1, b = t & 1;
        const float yr = b ? gbr[2] : gar[2], yi = b ? gbi[2] : gai[2];
        c3r[t] = c2r_[h] * yr - c2i_[h] * yi;
        c3i[t] = c2r_[h] * yi + c2i_[h] * yr;
    }
    float c4r[16], c4i[16];
#pragma unroll
    for (int t = 0; t < 16; ++t) {
        const int h = t >> 1, b = t & 1;
        const float yr = b ? gbr[3] : gar[3], yi = b ? gbi[3] : gai[3];
        c4r[t] = c3r[h] * yr - c3i[h] * yi;
        c4i[t] = c3r[h] * yi + c3i[h] * yr;
    }
    float c5r[32], c5i[32];
#pragma unroll
    for (int t = 0; t < 32; ++t) {
        const int h = t >> 1, b = t & 1;
        const float yr = b ? gbr[4] : gar[4], yi = b ? gbi[4] : gai[4];
        c5r[t] = c4r[h] * yr - c4i[h] * yi;
        c5i[t] = c4r[h] * yi + c4i[h] * yr;
    }
    float pr[DIM], pim[DIM];
#pragma unroll
    for (int t = 0; t < DIM; ++t) {
        const int h = t >> 1, b = t & 1;
        const float yr = b ? gbr[5] : gar[5], yi = b ? gbi[5] : gai[5];
        pr[t]  = c5r[h] * yr - c5i[h] * yi;
        pim[t] = c5r[h] * yi + c5i[h] * yr;
    }
    // (ring 1 after layer 0 is implicit: M1 composed into layer-1 indices)

    // ---- layers 1 (shared[1], then ring2) and 2 (task, then ring1) ----
    if constexpr (USE_WS) {
        gate_layer<1>(pr, pim, ws + 48);
        gate_layer<2>(pr, pim, ws + 96);
    } else {
        compute_gates6(th_s + 18, gfall);
        gate_layer<1>(pr, pim, gfall);
        compute_gates6(th_t, gfall);
        gate_layer<2>(pr, pim, gfall);
    }

    // ---- <Z_w> readout through M3 ----
    float q[6] = {0.f, 0.f, 0.f, 0.f, 0.f, 0.f};
    readout_impl(pr, pim, q, std::make_integer_sequence<int, DIM>{});

    // ---- head: out = q @ Wc^T + bc ----
#pragma unroll
    for (int n = 0; n < 5; ++n) {
        float o = bc[n];
#pragma unroll
        for (int w = 0; w < 6; ++w) o = fmaf(q[w], Wc[n * 6 + w], o);
        out[(long)row * 5 + n] = o;
    }
}

extern "C" void kernel_launch(void* const* d_in, const int* in_sizes, int n_in,
                              void* d_out, int out_size, void* d_ws, size_t ws_size,
                              hipStream_t stream) {
    const float* x   = (const float*)d_in[0];
    const float* W1  = (const float*)d_in[1];
    const float* b1  = (const float*)d_in[2];
    const float* lng = (const float*)d_in[3];
    const float* lnb = (const float*)d_in[4];
    const float* W2  = (const float*)d_in[5];
    const float* b2  = (const float*)d_in[6];
    const float* ths = (const float*)d_in[7];
    const float* tht = (const float*)d_in[8];
    const float* Wc  = (const float*)d_in[9];
    const float* bc  = (const float*)d_in[10];
    float* out = (float*)d_out;
    float* ws  = (float*)d_ws;

    const int nrows = in_sizes[0] / 64;          // 131072
    const int grid  = (nrows + 255) / 256;

    if (ws_size >= 540 * sizeof(float)) {
        setup_kernel<<<1, 384, 0, stream>>>(ths, tht, lng, lnb, W2, b2, ws);
        qmaml_kernel<true><<<grid, 256, 0, stream>>>(x, W1, b1, lng, lnb, W2, b2,
                                                     ths, tht, Wc, bc, ws, out, nrows);
    } else {
        qmaml_kernel<false><<<grid, 256, 0, stream>>>(x, W1, b1, lng, lnb, W2, b2,
                                                      ths, tht, Wc, bc, nullptr, out, nrows);
    }
}

// Round 3
// 157.595 us; speedup vs baseline: 1.5697x; 1.2786x over previous
//
#include <hip/hip_runtime.h>
#include <utility>

#define NQ 6
#define DIM 64

namespace {

// ---- compile-time ring permutation (CNOT ladder), matching _ring_perm ----
constexpr int ring_entry(int r, int i) {
    int idx = i;
    for (int w = NQ - 1; w >= 0; --w) {
        int c = w;
        int t = (w + r) % NQ;
        int cbit = (idx >> (NQ - 1 - c)) & 1;
        idx ^= cbit << (NQ - 1 - t);
    }
    return idx;
}

constexpr int ring_inv(int r, int j) {
    for (int i = 0; i < DIM; ++i) if (ring_entry(r, i) == j) return i;
    return -1;
}

// k-th index (k in [0,16)) of 5-bit local with bit b clear
constexpr int insert_zero(int k, int b) {
    return ((k >> b) << (b + 1)) | (k & ((1 << b) - 1));
}

} // namespace

// ---- wires 1..5: in-lane gates, 16 constexpr pairs per lane ----
template<int W, int... K>
__device__ __forceinline__ void wire_inlane_impl(float* sr, float* si,
        const float* __restrict__ g, std::integer_sequence<int, K...>) {
    const float u00r = g[0], u00i = g[1], u01r = g[2], u01i = g[3];
    const float u10r = g[4], u10i = g[5], u11r = g[6], u11i = g[7];
    constexpr int b = 5 - W;
    (([&] {
        constexpr int l0 = insert_zero(K, b);
        constexpr int l1 = l0 | (1 << b);
        const float ar = sr[l0], ai = si[l0];
        const float br = sr[l1], bi = si[l1];
        sr[l0] = u00r*ar - u00i*ai + u01r*br - u01i*bi;
        si[l0] = u00r*ai + u00i*ar + u01r*bi + u01i*br;
        sr[l1] = u10r*ar - u10i*ai + u11r*br - u11i*bi;
        si[l1] = u10r*ai + u10i*ar + u11r*bi + u11i*br;
    }()), ...);
}

// ---- wire 0: cross-lane gate. Even lane = role 0, odd = role 1 ----
__device__ __forceinline__ void wire0_cross(float* sr, float* si,
        const float* __restrict__ g, bool par) {
    const float cAr = par ? g[6] : g[0];   // coeff on MY amp
    const float cAi = par ? g[7] : g[1];
    const float cBr = par ? g[4] : g[2];   // coeff on PARTNER amp
    const float cBi = par ? g[5] : g[3];
#pragma unroll
    for (int l = 0; l < 32; ++l) {
        const float mr = sr[l], mi = si[l];
        const float tr = __shfl_xor(mr, 1, 64);
        const float ti = __shfl_xor(mi, 1, 64);
        sr[l] = cAr*mr - cAi*mi + cBr*tr - cBi*ti;
        si[l] = cAr*mi + cAi*mr + cBr*ti + cBi*tr;
    }
}

__device__ __forceinline__ void layer(float* sr, float* si,
        const float* __restrict__ g, bool par) {
    wire0_cross(sr, si, g, par);
    wire_inlane_impl<1>(sr, si, g + 8,  std::make_integer_sequence<int, 16>{});
    wire_inlane_impl<2>(sr, si, g + 16, std::make_integer_sequence<int, 16>{});
    wire_inlane_impl<3>(sr, si, g + 24, std::make_integer_sequence<int, 16>{});
    wire_inlane_impl<4>(sr, si, g + 32, std::make_integer_sequence<int, 16>{});
    wire_inlane_impl<5>(sr, si, g + 40, std::make_integer_sequence<int, 16>{});
}

// ---- ring permutation new[i] = old[R(i)], i = parity*32 + l ----
// src = R(l) ^ par*R(32). R1(32)=48, R2(32)=40: both have bit5 set.
template<int R, int... L>
__device__ __forceinline__ void ring_impl(float* sr, float* si, bool par,
                                          std::integer_sequence<int, L...>) {
    constexpr int C = ring_entry(R, 32);
    static_assert(((C >> 5) & 1) == 1, "lane-crossing structure assumed");
    constexpr int d = C & 31;
    float nr[32], ni[32];
    (([&] {
        constexpr int ql = ring_entry(R, L);
        constexpr int a  = ql & 31;
        constexpr bool cross = (ql >> 5) & 1;
        if constexpr (cross) {
            // partner sends old[a ^ ((its_par^1)*d)]; I receive old_partner[a ^ par*d]
            const float er = par ? sr[a] : sr[a ^ d];
            const float ei = par ? si[a] : si[a ^ d];
            nr[L] = __shfl_xor(er, 1, 64);
            ni[L] = __shfl_xor(ei, 1, 64);
        } else {
            nr[L] = par ? sr[a ^ d] : sr[a];
            ni[L] = par ? si[a ^ d] : si[a];
        }
    }()), ...);
    (((sr[L] = nr[L]), (si[L] = ni[L])), ...);
}

// ---- readout with final ring (R1) folded into constexpr signs ----
template<int... L>
__device__ __forceinline__ void readout_impl(const float* sr, const float* si, float* q,
                                             std::integer_sequence<int, L...>) {
    (([&] {
        constexpr int inv = ring_inv(1, L);
        const float pb = sr[L]*sr[L] + si[L]*si[L];
        q[0] += ((inv >> 5) & 1) ? -pb : pb;
        q[1] += ((inv >> 4) & 1) ? -pb : pb;
        q[2] += ((inv >> 3) & 1) ? -pb : pb;
        q[3] += ((inv >> 2) & 1) ? -pb : pb;
        q[4] += ((inv >> 1) & 1) ? -pb : pb;
        q[5] += ( inv       & 1) ? -pb : pb;
    }()), ...);
}

// ---- per-thread gate computation (fallback path only) ----
__device__ __forceinline__ void compute_gates6(const float* __restrict__ th, float* g) {
#pragma unroll
    for (int w = 0; w < NQ; ++w) {
        const float phi = th[w*3+0], theta = th[w*3+1], omega = th[w*3+2];
        float s, c, sa, ca, sb, cb;
        __sincosf(0.5f * theta, &s, &c);
        __sincosf(0.5f * (phi + omega), &sa, &ca);
        __sincosf(0.5f * (phi - omega), &sb, &cb);
        g[w*8+0] =  ca * c;  g[w*8+1] = -sa * c;
        g[w*8+2] = -cb * s;  g[w*8+3] = -sb * s;
        g[w*8+4] =  cb * s;  g[w*8+5] = -sb * s;
        g[w*8+6] =  ca * c;  g[w*8+7] =  sa * c;
    }
}

// ---- setup: gates (18x8) + Gt[j][m] = ln_g[j]*W2[m][j] (64x6) + C1/C2 ----
// ws floats: [0,144) gates, [144,528) Gt (j*6+m), [528,534) C1, [534,540) C2+b2
__global__ void setup_kernel(const float* __restrict__ th_s, const float* __restrict__ th_t,
                             const float* __restrict__ ln_g, const float* __restrict__ ln_b,
                             const float* __restrict__ W2, const float* __restrict__ b2,
                             float* __restrict__ ws) {
    const int t = threadIdx.x;
    if (t < 18) {
        const int l = t / 6, w = t % 6;
        const float* th = (l < 2) ? (th_s + (l * 6 + w) * 3) : (th_t + w * 3);
        const float phi = th[0], theta = th[1], omega = th[2];
        float s, c, sa, ca, sb, cb;
        sincosf(0.5f * theta, &s, &c);
        sincosf(0.5f * (phi + omega), &sa, &ca);
        sincosf(0.5f * (phi - omega), &sb, &cb);
        float* g = ws + t * 8;
        g[0] =  ca * c;  g[1] = -sa * c;
        g[2] = -cb * s;  g[3] = -sb * s;
        g[4] =  cb * s;  g[5] = -sb * s;
        g[6] =  ca * c;  g[7] =  sa * c;
    }
    if (t < 384) {
        const int j = t / 6, m = t % 6;
        ws[144 + t] = ln_g[j] * W2[m * 64 + j];
    }
    if (t < 6) {
        float c1 = 0.f, c2 = 0.f;
        for (int j = 0; j < 64; ++j) {
            c1 += ln_g[j] * W2[t * 64 + j];
            c2 += ln_b[j] * W2[t * 64 + j];
        }
        ws[528 + t] = c1;
        ws[534 + t] = c2 + b2[t];
    }
}

template<bool USE_WS>
__global__ __launch_bounds__(256, 4)   // cap 128 VGPR, 4 waves/EU
void qmaml_kernel(
    const float* __restrict__ x,  const float* __restrict__ W1, const float* __restrict__ b1,
    const float* __restrict__ ln_g, const float* __restrict__ ln_b,
    const float* __restrict__ W2, const float* __restrict__ b2,
    const float* __restrict__ th_s, const float* __restrict__ th_t,
    const float* __restrict__ Wc, const float* __restrict__ bc,
    const float* __restrict__ ws, float* __restrict__ out, int nrows) {

    const int t   = blockIdx.x * 256 + threadIdx.x;
    const int row = t >> 1;
    const bool par = t & 1;            // = logical wire-0 bit of my half-state
    if (row >= nrows) return;

    // ---- load x row (both lanes of a pair load the same row) ----
    float4 xv[16];
    const float4* xp = (const float4*)(x + (long)row * 64);
#pragma unroll
    for (int k = 0; k < 16; ++k) xv[k] = xp[k];

    // ---- fused matvec + relu + LN-stats + folded (g*W2) projection ----
    // (redundant across the lane pair; keeps W1 loads wave-uniform s_loads)
    float A[6]  = {0.f, 0.f, 0.f, 0.f, 0.f, 0.f};
    float C1[6] = {0.f, 0.f, 0.f, 0.f, 0.f, 0.f};
    float C2[6] = {0.f, 0.f, 0.f, 0.f, 0.f, 0.f};
    float s = 0.f, s2 = 0.f;

    for (int j = 0; j < 64; ++j) {
        const float4* wr = (const float4*)(W1 + j * 64);
        float acc = b1[j];
#pragma unroll
        for (int k = 0; k < 16; ++k) {
            const float4 w4 = wr[k];
            acc = fmaf(w4.x, xv[k].x, acc);
            acc = fmaf(w4.y, xv[k].y, acc);
            acc = fmaf(w4.z, xv[k].z, acc);
            acc = fmaf(w4.w, xv[k].w, acc);
        }
        acc = fmaxf(acc, 0.f);
        s += acc; s2 += acc * acc;
        if constexpr (USE_WS) {
            const float* Gt = ws + 144 + j * 6;
#pragma unroll
            for (int m = 0; m < 6; ++m) A[m] = fmaf(acc, Gt[m], A[m]);
        } else {
            const float gj = ln_g[j], bj = ln_b[j];
#pragma unroll
            for (int m = 0; m < 6; ++m) {
                const float w2 = W2[m * 64 + j];
                const float gw = gj * w2;
                A[m]  = fmaf(acc, gw, A[m]);
                C1[m] += gw;
                C2[m] = fmaf(bj, w2, C2[m]);
            }
        }
    }

    const float mu  = s  * (1.f / 64.f);
    const float var = s2 * (1.f / 64.f) - mu * mu;
    const float inv = rsqrtf(var + 1e-5f);

    // ---- z = tanh(...), per-wire (cos, sin) ----
    float vc[6], vsn[6];
#pragma unroll
    for (int m = 0; m < 6; ++m) {
        float c1v, c2v;
        if constexpr (USE_WS) { c1v = ws[528 + m]; c2v = ws[534 + m]; }
        else                  { c1v = C1[m];       c2v = C2[m] + b2[m]; }
        const float zp = inv * (A[m] - mu * c1v) + c2v;
        const float e  = __expf(2.f * zp);
        const float z  = 1.f - 2.f / (e + 1.f);
        const float half = 1.57079632679f * z;
        vsn[m] = __sinf(half);
        vc[m]  = __cosf(half);
    }

    float gf[48];
    const float* g0;
    if constexpr (USE_WS) g0 = ws;
    else { compute_gates6(th_s, gf); g0 = gf; }

    // ---- layer-0 gates on per-wire product vectors ----
    float gar[6], gai[6], gbr[6], gbi[6];
#pragma unroll
    for (int w = 0; w < 6; ++w) {
        const float c = vc[w], sv = vsn[w];
        gar[w] = g0[w*8+0]*c + g0[w*8+2]*sv;
        gai[w] = g0[w*8+1]*c + g0[w*8+3]*sv;
        gbr[w] = g0[w*8+4]*c + g0[w*8+6]*sv;
        gbi[w] = g0[w*8+5]*c + g0[w*8+7]*sv;
    }

    // ---- build my half of the product state (32 amps; wire0 = parity) ----
    float c1r_[2], c1i_[2];
    {
        const float c0r = par ? gbr[0] : gar[0];
        const float c0i = par ? gbi[0] : gai[0];
#pragma unroll
        for (int k = 0; k < 2; ++k) {
            const float yr = k ? gbr[1] : gar[1], yi = k ? gbi[1] : gai[1];
            c1r_[k] = c0r * yr - c0i * yi;
            c1i_[k] = c0r * yi + c0i * yr;
        }
    }
    float c2r_[4], c2i_[4];
#pragma unroll
    for (int k = 0; k < 4; ++k) {
        const int h = k >> 1, b = k & 1;
        const float yr = b ? gbr[2] : gar[2], yi = b ? gbi[2] : gai[2];
        c2r_[k] = c1r_[h] * yr - c1i_[h] * yi;
        c2i_[k] = c1r_[h] * yi + c1i_[h] * yr;
    }
    float c3r[8], c3i[8];
#pragma unroll
    for (int k = 0; k < 8; ++k) {
        const int h = k >> 1, b = k & 1;
        const float yr = b ? gbr[3] : gar[3], yi = b ? gbi[3] : gai[3];
        c3r[k] = c2r_[h] * yr - c2i_[h] * yi;
        c3i[k] = c2r_[h] * yi + c2i_[h] * yr;
    }
    float c4r[16], c4i[16];
#pragma unroll
    for (int k = 0; k < 16; ++k) {
        const int h = k >> 1, b = k & 1;
        const float yr = b ? gbr[4] : gar[4], yi = b ? gbi[4] : gai[4];
        c4r[k] = c3r[h] * yr - c3i[h] * yi;
        c4i[k] = c3r[h] * yi + c3i[h] * yr;
    }
    float sr[32], si[32];
#pragma unroll
    for (int k = 0; k < 32; ++k) {
        const int h = k >> 1, b = k & 1;
        const float yr = b ? gbr[5] : gar[5], yi = b ? gbi[5] : gai[5];
        sr[k] = c4r[h] * yr - c4i[h] * yi;
        si[k] = c4r[h] * yi + c4i[h] * yr;
    }

    // ---- ring1 -> layer1 -> ring2 -> layer2 (ring1 after layer2 folded) ----
    ring_impl<1>(sr, si, par, std::make_integer_sequence<int, 32>{});
    if constexpr (USE_WS) {
        layer(sr, si, ws + 48, par);
        ring_impl<2>(sr, si, par, std::make_integer_sequence<int, 32>{});
        layer(sr, si, ws + 96, par);
    } else {
        compute_gates6(th_s + 18, gf);
        layer(sr, si, gf, par);
        ring_impl<2>(sr, si, par, std::make_integer_sequence<int, 32>{});
        compute_gates6(th_t, gf);
        layer(sr, si, gf, par);
    }

    // ---- readout (final R1 folded into signs via R1^-1) ----
    float q[6] = {0.f, 0.f, 0.f, 0.f, 0.f, 0.f};
    readout_impl(sr, si, q, std::make_integer_sequence<int, 32>{});

    const float pm = par ? -1.f : 1.f;
    constexpr int invC = ring_inv(1, 32);   // parity contribution to R1^-1
#pragma unroll
    for (int w = 0; w < 6; ++w) {
        float tq = q[w];
        if ((invC >> (5 - w)) & 1) tq *= pm;
        q[w] = tq + __shfl_xor(tq, 1, 64);
    }

    // ---- head: out = q @ Wc^T + bc (split store across the lane pair) ----
    float o[5];
#pragma unroll
    for (int n = 0; n < 5; ++n) {
        float v = bc[n];
#pragma unroll
        for (int w = 0; w < 6; ++w) v = fmaf(q[w], Wc[n * 6 + w], v);
        o[n] = v;
    }
    float* orow = out + (long)row * 5;
    if (!par) { orow[0] = o[0]; orow[1] = o[1]; orow[2] = o[2]; }
    else      { orow[3] = o[3]; orow[4] = o[4]; }
}

extern "C" void kernel_launch(void* const* d_in, const int* in_sizes, int n_in,
                              void* d_out, int out_size, void* d_ws, size_t ws_size,
                              hipStream_t stream) {
    const float* x   = (const float*)d_in[0];
    const float* W1  = (const float*)d_in[1];
    const float* b1  = (const float*)d_in[2];
    const float* lng = (const float*)d_in[3];
    const float* lnb = (const float*)d_in[4];
    const float* W2  = (const float*)d_in[5];
    const float* b2  = (const float*)d_in[6];
    const float* ths = (const float*)d_in[7];
    const float* tht = (const float*)d_in[8];
    const float* Wc  = (const float*)d_in[9];
    const float* bc  = (const float*)d_in[10];
    float* out = (float*)d_out;
    float* ws  = (float*)d_ws;

    const int nrows = in_sizes[0] / 64;              // 131072
    const int nthreads = nrows * 2;                  // 2 lanes per row
    const int grid = (nthreads + 255) / 256;

    if (ws_size >= 540 * sizeof(float)) {
        setup_kernel<<<1, 384, 0, stream>>>(ths, tht, lng, lnb, W2, b2, ws);
        qmaml_kernel<true><<<grid, 256, 0, stream>>>(x, W1, b1, lng, lnb, W2, b2,
                                                     ths, tht, Wc, bc, ws, out, nrows);
    } else {
        qmaml_kernel<false><<<grid, 256, 0, stream>>>(x, W1, b1, lng, lnb, W2, b2,
                                                      ths, tht, Wc, bc, nullptr, out, nrows);
    }
}

// Round 4
// 155.939 us; speedup vs baseline: 1.5863x; 1.0106x over previous
//
#include <hip/hip_runtime.h>
#include <utility>

#define NQ 6
#define DIM 64

namespace {

// ---- compile-time ring permutation (CNOT ladder), matching _ring_perm ----
constexpr int ring_entry(int r, int i) {
    int idx = i;
    for (int w = NQ - 1; w >= 0; --w) {
        int c = w;
        int t = (w + r) % NQ;
        int cbit = (idx >> (NQ - 1 - c)) & 1;
        idx ^= cbit << (NQ - 1 - t);
    }
    return idx;
}

// Logical->physical composed map after L rings (all rings are GF(2)-linear).
// Rings in order: R1 (after layer0), R2 (after layer1), R1 (after layer2).
constexpr int Mc(int L, int i) {
    if (L == 1) return ring_entry(1, i);
    if (L == 2) return ring_entry(1, ring_entry(2, i));
    if (L == 3) return ring_entry(1, ring_entry(2, ring_entry(1, i)));
    return i;
}

constexpr int Minv(int L, int p) {
    for (int i = 0; i < DIM; ++i) if (Mc(L, i) == p) return i;
    return -1;
}

} // namespace

// ---- 1-instr VALU lane swap (pairs 2r<->2r+1): DPP quad_perm [1,0,3,2] ----
__device__ __forceinline__ float swap1(float v) {
    return __int_as_float(__builtin_amdgcn_mov_dpp(__float_as_int(v), 0xB1, 0xF, 0xF, true));
}

// ===== gate application in the fixed physical frame via composed maps =====
// storage: my 32 regs hold physical slots (par, l); logical i = Minv(L, p).

template<int LY, int W, int d, int... Ls>
__device__ __forceinline__ void wire_inlane(float* sr, float* si,
        float A0r, float A0i, float B0r, float B0i,
        float A1r, float A1i, float B1r, float B1i,
        std::integer_sequence<int, Ls...>) {
    (([&] {
        if constexpr (Ls < (Ls ^ d)) {
            constexpr int la = Ls, lb = Ls ^ d;
            constexpr int ra = (Minv(LY, la) >> (5 - W)) & 1;
            constexpr int rb = (Minv(LY, lb) >> (5 - W)) & 1;
            const float cAar = ra ? A1r : A0r, cAai = ra ? A1i : A0i;
            const float cBar = ra ? B1r : B0r, cBai = ra ? B1i : B0i;
            const float cAbr = rb ? A1r : A0r, cAbi = rb ? A1i : A0i;
            const float cBbr = rb ? B1r : B0r, cBbi = rb ? B1i : B0i;
            const float mar = sr[la], mai = si[la];
            const float mbr = sr[lb], mbi = si[lb];
            sr[la] = cAar*mar - cAai*mai + cBar*mbr - cBai*mbi;
            si[la] = cAar*mai + cAai*mar + cBar*mbi + cBai*mbr;
            sr[lb] = cAbr*mbr - cAbi*mbi + cBbr*mar - cBbi*mai;
            si[lb] = cAbr*mbi + cAbi*mbr + cBbr*mai + cBbi*mar;
        }
    }()), ...);
}

template<int LY, int W, int... Ls>
__device__ __forceinline__ void wire_cross0(float* sr, float* si,
        float A0r, float A0i, float B0r, float B0i,
        float A1r, float A1i, float B1r, float B1i,
        std::integer_sequence<int, Ls...>) {
    (([&] {
        constexpr int r = (Minv(LY, Ls) >> (5 - W)) & 1;
        const float cAr = r ? A1r : A0r, cAi = r ? A1i : A0i;
        const float cBr = r ? B1r : B0r, cBi = r ? B1i : B0i;
        const float mr = sr[Ls], mi = si[Ls];
        const float tr = swap1(mr), ti = swap1(mi);   // reads precede writes (lockstep)
        sr[Ls] = cAr*mr - cAi*mi + cBr*tr - cBi*ti;
        si[Ls] = cAr*mi + cAi*mr + cBr*ti + cBi*tr;
    }()), ...);
}

template<int LY, int W, int d, int... Ls>
__device__ __forceinline__ void wire_crossd(float* sr, float* si,
        float A0r, float A0i, float B0r, float B0i,
        float A1r, float A1i, float B1r, float B1i,
        std::integer_sequence<int, Ls...>) {
    (([&] {
        if constexpr (Ls < (Ls ^ d)) {
            constexpr int la = Ls, lb = Ls ^ d;
            constexpr int ra = (Minv(LY, la) >> (5 - W)) & 1;
            constexpr int rb = (Minv(LY, lb) >> (5 - W)) & 1;
            const float cAar = ra ? A1r : A0r, cAai = ra ? A1i : A0i;
            const float cBar = ra ? B1r : B0r, cBai = ra ? B1i : B0i;
            const float cAbr = rb ? A1r : A0r, cAbi = rb ? A1i : A0i;
            const float cBbr = rb ? B1r : B0r, cBbi = rb ? B1i : B0i;
            const float mar = sr[la], mai = si[la];
            const float mbr = sr[lb], mbi = si[lb];
            const float tar = swap1(mbr), tai_ = swap1(mbi);  // partner old [lb]
            const float tbr = swap1(mar), tbi_ = swap1(mai);  // partner old [la]
            sr[la] = cAar*mar - cAai*mai + cBar*tar - cBai*tai_;
            si[la] = cAar*mai + cAai*mar + cBar*tai_ + cBai*tar;
            sr[lb] = cAbr*mbr - cAbi*mbi + cBbr*tbr - cBbi*tbi_;
            si[lb] = cAbr*mbi + cAbi*mbr + cBbr*tbi_ + cBbi*tbr;
        }
    }()), ...);
}

template<int LY, int W>
__device__ __forceinline__ void wire_apply(float* sr, float* si,
        const float* __restrict__ g, bool par) {
    constexpr int D = Mc(LY, 1 << (5 - W));     // physical pair offset (linear map)
    constexpr bool cross = (D >> 5) & 1;
    constexpr int d = D & 31;
    constexpr bool cpar = (Minv(LY, 32) >> (5 - W)) & 1;  // role flips with parity

    // role-hoisted coefficients: slot role = r0(l) ^ (par && cpar)
    float A0r, A0i, B0r, B0i, A1r, A1i, B1r, B1i;
    if constexpr (cpar) {
        A0r = par ? g[6] : g[0];  A0i = par ? g[7] : g[1];
        B0r = par ? g[4] : g[2];  B0i = par ? g[5] : g[3];
        A1r = par ? g[0] : g[6];  A1i = par ? g[1] : g[7];
        B1r = par ? g[2] : g[4];  B1i = par ? g[3] : g[5];
    } else {
        A0r = g[0]; A0i = g[1]; B0r = g[2]; B0i = g[3];
        A1r = g[6]; A1i = g[7]; B1r = g[4]; B1i = g[5];
    }
    if constexpr (!cross) {
        wire_inlane<LY, W, d>(sr, si, A0r, A0i, B0r, B0i, A1r, A1i, B1r, B1i,
                              std::make_integer_sequence<int, 32>{});
    } else if constexpr (d == 0) {
        wire_cross0<LY, W>(sr, si, A0r, A0i, B0r, B0i, A1r, A1i, B1r, B1i,
                           std::make_integer_sequence<int, 32>{});
    } else {
        wire_crossd<LY, W, d>(sr, si, A0r, A0i, B0r, B0i, A1r, A1i, B1r, B1i,
                              std::make_integer_sequence<int, 32>{});
    }
}

template<int LY>
__device__ __forceinline__ void layer_apply(float* sr, float* si,
        const float* __restrict__ g, bool par) {
    wire_apply<LY, 0>(sr, si, g,      par);
    wire_apply<LY, 1>(sr, si, g + 8,  par);
    wire_apply<LY, 2>(sr, si, g + 16, par);
    wire_apply<LY, 3>(sr, si, g + 24, par);
    wire_apply<LY, 4>(sr, si, g + 32, par);
    wire_apply<LY, 5>(sr, si, g + 40, par);
}

// ---- readout: fold full M3 into constexpr signs + one parity flip ----
template<int... Ls>
__device__ __forceinline__ void readout_impl(const float* sr, const float* si, float* q,
                                             std::integer_sequence<int, Ls...>) {
    (([&] {
        constexpr int iv = Minv(3, Ls);
        const float pb = sr[Ls]*sr[Ls] + si[Ls]*si[Ls];
        q[0] += ((iv >> 5) & 1) ? -pb : pb;
        q[1] += ((iv >> 4) & 1) ? -pb : pb;
        q[2] += ((iv >> 3) & 1) ? -pb : pb;
        q[3] += ((iv >> 2) & 1) ? -pb : pb;
        q[4] += ((iv >> 1) & 1) ? -pb : pb;
        q[5] += ( iv       & 1) ? -pb : pb;
    }()), ...);
}

// ---- per-thread gate computation (fallback path only) ----
__device__ __forceinline__ void compute_gates6(const float* __restrict__ th, float* g) {
#pragma unroll
    for (int w = 0; w < NQ; ++w) {
        const float phi = th[w*3+0], theta = th[w*3+1], omega = th[w*3+2];
        float s, c, sa, ca, sb, cb;
        __sincosf(0.5f * theta, &s, &c);
        __sincosf(0.5f * (phi + omega), &sa, &ca);
        __sincosf(0.5f * (phi - omega), &sb, &cb);
        g[w*8+0] =  ca * c;  g[w*8+1] = -sa * c;
        g[w*8+2] = -cb * s;  g[w*8+3] = -sb * s;
        g[w*8+4] =  cb * s;  g[w*8+5] = -sb * s;
        g[w*8+6] =  ca * c;  g[w*8+7] =  sa * c;
    }
}

// ---- setup: gates (18x8) + Gt[j][m] = ln_g[j]*W2[m][j] (64x6) + C1/C2 ----
// ws floats: [0,144) gates, [144,528) Gt (j*6+m), [528,534) C1, [534,540) C2+b2
__global__ void setup_kernel(const float* __restrict__ th_s, const float* __restrict__ th_t,
                             const float* __restrict__ ln_g, const float* __restrict__ ln_b,
                             const float* __restrict__ W2, const float* __restrict__ b2,
                             float* __restrict__ ws) {
    const int t = threadIdx.x;
    if (t < 18) {
        const int l = t / 6, w = t % 6;
        const float* th = (l < 2) ? (th_s + (l * 6 + w) * 3) : (th_t + w * 3);
        const float phi = th[0], theta = th[1], omega = th[2];
        float s, c, sa, ca, sb, cb;
        sincosf(0.5f * theta, &s, &c);
        sincosf(0.5f * (phi + omega), &sa, &ca);
        sincosf(0.5f * (phi - omega), &sb, &cb);
        float* g = ws + t * 8;
        g[0] =  ca * c;  g[1] = -sa * c;
        g[2] = -cb * s;  g[3] = -sb * s;
        g[4] =  cb * s;  g[5] = -sb * s;
        g[6] =  ca * c;  g[7] =  sa * c;
    }
    if (t < 384) {
        const int j = t / 6, m = t % 6;
        ws[144 + t] = ln_g[j] * W2[m * 64 + j];
    }
    if (t < 6) {
        float c1 = 0.f, c2 = 0.f;
        for (int j = 0; j < 64; ++j) {
            c1 += ln_g[j] * W2[t * 64 + j];
            c2 += ln_b[j] * W2[t * 64 + j];
        }
        ws[528 + t] = c1;
        ws[534 + t] = c2 + b2[t];
    }
}

template<bool USE_WS>
__global__ __launch_bounds__(256, 4)   // cap 128 VGPR, 4 waves/EU
void qmaml_kernel(
    const float* __restrict__ x,  const float* __restrict__ W1, const float* __restrict__ b1,
    const float* __restrict__ ln_g, const float* __restrict__ ln_b,
    const float* __restrict__ W2, const float* __restrict__ b2,
    const float* __restrict__ th_s, const float* __restrict__ th_t,
    const float* __restrict__ Wc, const float* __restrict__ bc,
    const float* __restrict__ ws, float* __restrict__ out, int nrows) {

    const int t   = blockIdx.x * 256 + threadIdx.x;
    const int row = t >> 1;
    const bool par = t & 1;            // = logical wire-0 bit of my half-state
    if (row >= nrows) return;

    // ---- load x row (both lanes of a pair load the same row) ----
    float4 xv[16];
    const float4* xp = (const float4*)(x + (long)row * 64);
#pragma unroll
    for (int k = 0; k < 16; ++k) xv[k] = xp[k];

    // ---- fused matvec + relu + LN-stats + folded (g*W2) projection ----
    float A[6]  = {0.f, 0.f, 0.f, 0.f, 0.f, 0.f};
    float C1[6] = {0.f, 0.f, 0.f, 0.f, 0.f, 0.f};
    float C2[6] = {0.f, 0.f, 0.f, 0.f, 0.f, 0.f};
    float s = 0.f, s2 = 0.f;

    for (int j = 0; j < 64; ++j) {     // rolled; W1 row via wave-uniform s_load
        const float4* wr = (const float4*)(W1 + j * 64);
        float acc = b1[j];
#pragma unroll
        for (int k = 0; k < 16; ++k) {
            const float4 w4 = wr[k];
            acc = fmaf(w4.x, xv[k].x, acc);
            acc = fmaf(w4.y, xv[k].y, acc);
            acc = fmaf(w4.z, xv[k].z, acc);
            acc = fmaf(w4.w, xv[k].w, acc);
        }
        acc = fmaxf(acc, 0.f);
        s += acc; s2 += acc * acc;
        if constexpr (USE_WS) {
            const float* Gt = ws + 144 + j * 6;
#pragma unroll
            for (int m = 0; m < 6; ++m) A[m] = fmaf(acc, Gt[m], A[m]);
        } else {
            const float gj = ln_g[j], bj = ln_b[j];
#pragma unroll
            for (int m = 0; m < 6; ++m) {
                const float w2 = W2[m * 64 + j];
                const float gw = gj * w2;
                A[m]  = fmaf(acc, gw, A[m]);
                C1[m] += gw;
                C2[m] = fmaf(bj, w2, C2[m]);
            }
        }
    }

    const float mu  = s  * (1.f / 64.f);
    const float var = s2 * (1.f / 64.f) - mu * mu;
    const float inv = rsqrtf(var + 1e-5f);

    // ---- z = tanh(...), per-wire (cos, sin) ----
    float vc[6], vsn[6];
#pragma unroll
    for (int m = 0; m < 6; ++m) {
        float c1v, c2v;
        if constexpr (USE_WS) { c1v = ws[528 + m]; c2v = ws[534 + m]; }
        else                  { c1v = C1[m];       c2v = C2[m] + b2[m]; }
        const float zp = inv * (A[m] - mu * c1v) + c2v;
        const float e  = __expf(2.f * zp);
        const float z  = 1.f - 2.f / (e + 1.f);
        const float half = 1.57079632679f * z;
        vsn[m] = __sinf(half);
        vc[m]  = __cosf(half);
    }

    float gf[48];
    const float* g0;
    if constexpr (USE_WS) g0 = ws;
    else { compute_gates6(th_s, gf); g0 = gf; }

    // ---- layer-0 gates folded into per-wire product vectors ----
    float gar[6], gai[6], gbr[6], gbi[6];
#pragma unroll
    for (int w = 0; w < 6; ++w) {
        const float c = vc[w], sv = vsn[w];
        gar[w] = g0[w*8+0]*c + g0[w*8+2]*sv;
        gai[w] = g0[w*8+1]*c + g0[w*8+3]*sv;
        gbr[w] = g0[w*8+4]*c + g0[w*8+6]*sv;
        gbi[w] = g0[w*8+5]*c + g0[w*8+7]*sv;
    }

    // ---- build my half of the product state (32 amps; wire0 = parity) ----
    float c1r_[2], c1i_[2];
    {
        const float c0r = par ? gbr[0] : gar[0];
        const float c0i = par ? gbi[0] : gai[0];
#pragma unroll
        for (int k = 0; k < 2; ++k) {
            const float yr = k ? gbr[1] : gar[1], yi = k ? gbi[1] : gai[1];
            c1r_[k] = c0r * yr - c0i * yi;
            c1i_[k] = c0r * yi + c0i * yr;
        }
    }
    float c2r_[4], c2i_[4];
#pragma unroll
    for (int k = 0; k < 4; ++k) {
        const int h = k >> 1, b = k & 1;
        const float yr = b ? gbr[2] : gar[2], yi = b ? gbi[2] : gai[2];
        c2r_[k] = c1r_[h] * yr - c1i_[h] * yi;
        c2i_[k] = c1r_[h] * yi + c1i_[h] * yr;
    }
    float c3r[8], c3i[8];
#pragma unroll
    for (int k = 0; k < 8; ++k) {
        const int h = k >> 1, b = k & 1;
        const float yr = b ? gbr[3] : gar[3], yi = b ? gbi[3] : gai[3];
        c3r[k] = c2r_[h] * yr - c2i_[h] * yi;
        c3i[k] = c2r_[h] * yi + c2i_[h] * yr;
    }
    float c4r[16], c4i[16];
#pragma unroll
    for (int k = 0; k < 16; ++k) {
        const int h = k >> 1, b = k & 1;
        const float yr = b ? gbr[4] : gar[4], yi = b ? gbi[4] : gai[4];
        c4r[k] = c3r[h] * yr - c3i[h] * yi;
        c4i[k] = c3r[h] * yi + c3i[h] * yr;
    }
    float sr[32], si[32];
#pragma unroll
    for (int k = 0; k < 32; ++k) {
        const int h = k >> 1, b = k & 1;
        const float yr = b ? gbr[5] : gar[5], yi = b ? gbi[5] : gai[5];
        sr[k] = c4r[h] * yr - c4i[h] * yi;
        si[k] = c4r[h] * yi + c4i[h] * yr;
    }

    // ---- layers act through composed maps; NO physical permutations ----
    if constexpr (USE_WS) {
        layer_apply<1>(sr, si, ws + 48, par);
        layer_apply<2>(sr, si, ws + 96, par);
    } else {
        compute_gates6(th_s + 18, gf);
        layer_apply<1>(sr, si, gf, par);
        compute_gates6(th_t, gf);
        layer_apply<2>(sr, si, gf, par);
    }

    // ---- <Z_w> readout through M3 ----
    float q[6] = {0.f, 0.f, 0.f, 0.f, 0.f, 0.f};
    readout_impl(sr, si, q, std::make_integer_sequence<int, 32>{});

    const float pm = par ? -1.f : 1.f;
    constexpr int invC = Minv(3, 32);   // parity contribution to M3^-1
#pragma unroll
    for (int w = 0; w < 6; ++w) {
        float tq = q[w];
        if ((invC >> (5 - w)) & 1) tq *= pm;
        q[w] = tq + swap1(tq);
    }

    // ---- head: out = q @ Wc^T + bc (split store across the lane pair) ----
    float o[5];
#pragma unroll
    for (int n = 0; n < 5; ++n) {
        float v = bc[n];
#pragma unroll
        for (int w = 0; w < 6; ++w) v = fmaf(q[w], Wc[n * 6 + w], v);
        o[n] = v;
    }
    float* orow = out + (long)row * 5;
    if (!par) { orow[0] = o[0]; orow[1] = o[1]; orow[2] = o[2]; }
    else      { orow[3] = o[3]; orow[4] = o[4]; }
}

extern "C" void kernel_launch(void* const* d_in, const int* in_sizes, int n_in,
                              void* d_out, int out_size, void* d_ws, size_t ws_size,
                              hipStream_t stream) {
    const float* x   = (const float*)d_in[0];
    const float* W1  = (const float*)d_in[1];
    const float* b1  = (const float*)d_in[2];
    const float* lng = (const float*)d_in[3];
    const float* lnb = (const float*)d_in[4];
    const float* W2  = (const float*)d_in[5];
    const float* b2  = (const float*)d_in[6];
    const float* ths = (const float*)d_in[7];
    const float* tht = (const float*)d_in[8];
    const float* Wc  = (const float*)d_in[9];
    const float* bc  = (const float*)d_in[10];
    float* out = (float*)d_out;
    float* ws  = (float*)d_ws;

    const int nrows = in_sizes[0] / 64;              // 131072
    const int nthreads = nrows * 2;                  // 2 lanes per row
    const int grid = (nthreads + 255) / 256;

    if (ws_size >= 540 * sizeof(float)) {
        setup_kernel<<<1, 384, 0, stream>>>(ths, tht, lng, lnb, W2, b2, ws);
        qmaml_kernel<true><<<grid, 256, 0, stream>>>(x, W1, b1, lng, lnb, W2, b2,
                                                     ths, tht, Wc, bc, ws, out, nrows);
    } else {
        qmaml_kernel<false><<<grid, 256, 0, stream>>>(x, W1, b1, lng, lnb, W2, b2,
                                                      ths, tht, Wc, bc, nullptr, out, nrows);
    }
}